// Round 3
// baseline (488.754 us; speedup 1.0000x reference)
//
#include <hip/hip_runtime.h>

typedef unsigned short u16;
typedef unsigned int u32;
typedef __attribute__((ext_vector_type(8))) short short8v;
typedef __attribute__((ext_vector_type(4))) short short4v;
typedef __attribute__((ext_vector_type(4))) float floatx4;

#define BB 4
#define SS 2048
#define DD 1024
#define HH 16
#define DKK 64
#define MM (BB * SS)   // 8192
#define KK DD
#define NN DD
// log2(e)/sqrt(DK): folded into Q projection so scores are ready for exp2
#define QSCALE 0.18033688011112042f

// Ps padded layout: row stride 12 u16, chunk (k-octet) stride 200 u16.
#define PS_RS 12
#define PS_CS 200
#define PS_REGION 1600  // 8 chunks

__device__ __forceinline__ u16 f2bf(float f) {
  union { __bf16 h; u16 u; } r; r.h = (__bf16)f; return r.u;
}
__device__ __forceinline__ u32 pack2bf(float a, float b) {
  union { u32 u; __bf16 h[2]; } r;
  r.h[0] = (__bf16)a; r.h[1] = (__bf16)b; return r.u;
}

__device__ __forceinline__ void load_lds16(const void* g, void* l) {
  __builtin_amdgcn_global_load_lds((const __attribute__((address_space(1))) void*)g,
                                   (__attribute__((address_space(3))) void*)l, 16, 0, 0);
}

__device__ __forceinline__ floatx4 mfma_bf16(short8v a, short8v b, floatx4 c) {
  return __builtin_amdgcn_mfma_f32_16x16x32_bf16(a, b, c, 0, 0, 0);
}

// ---------------- fp32 -> bf16 convert ----------------
__global__ __launch_bounds__(256) void cvt_bf16(const float* __restrict__ in,
                                                u16* __restrict__ out, int n) {
  int i = (blockIdx.x * 256 + threadIdx.x) * 8;
  if (i + 8 > n) return;
  float4 a = *(const float4*)(in + i);
  float4 b = *(const float4*)(in + i + 4);
  uint4 o;
  o.x = pack2bf(a.x, a.y); o.y = pack2bf(a.z, a.w);
  o.z = pack2bf(b.x, b.y); o.w = pack2bf(b.z, b.w);
  *(uint4*)(out + i) = o;
}

// ---------------- GEMM-BT: out = A @ W^T + bias, 128x128 tile, BK=32 ----------------
// A bf16 [M,K]; W bf16 [N,K].
// EPI 0: bf16 [M,N] ; 1: bf16 [M,N] * QSCALE ; 2: bf16 V^T [B,H,DK,S] packed b64 ;
// EPI 3: fp32 [M,N].
template <int EPI>
__global__ __launch_bounds__(256) void gemm_bt(const u16* __restrict__ A,
                                               const u16* __restrict__ W,
                                               const float* __restrict__ bias,
                                               void* __restrict__ outv) {
  __shared__ __align__(16) u16 As[128 * 32];
  __shared__ __align__(16) u16 Bs[128 * 32];
  const int tid = threadIdx.x;
  const int w = tid >> 6, lane = tid & 63;
  const int lr = lane & 15, lq = lane >> 4;
  const int m0 = blockIdx.x * 128, n0 = blockIdx.y * 128;
  const int wr = w >> 1, wc = w & 1;

  floatx4 acc[4][4] = {};

  const u16* ga0 = A + (size_t)(m0 + 2 * w * 16 + lr) * KK + lq * 8;
  const u16* ga1 = ga0 + 16 * KK;
  const u16* gb0 = W + (size_t)(n0 + 2 * w * 16 + lr) * KK + lq * 8;
  const u16* gb1 = gb0 + 16 * KK;
  u16* la0 = &As[(2 * w) * 512]; u16* la1 = la0 + 512;
  u16* lb0 = &Bs[(2 * w) * 512]; u16* lb1 = lb0 + 512;

  for (int k0 = 0; k0 < KK; k0 += 32) {
    load_lds16(ga0 + k0, la0);
    load_lds16(ga1 + k0, la1);
    load_lds16(gb0 + k0, lb0);
    load_lds16(gb1 + k0, lb1);
    __syncthreads();
    short8v af[4], bf[4];
#pragma unroll
    for (int i = 0; i < 4; ++i) {
      af[i] = *(const short8v*)&As[(wr * 4 + i) * 512 + lane * 8];
      bf[i] = *(const short8v*)&Bs[(wc * 4 + i) * 512 + lane * 8];
    }
#pragma unroll
    for (int i = 0; i < 4; ++i)
#pragma unroll
      for (int j = 0; j < 4; ++j)
        acc[i][j] = mfma_bf16(af[i], bf[j], acc[i][j]);
    __syncthreads();
  }

  if (EPI == 2) {
    // V^T store: r=0..3 are 4 consecutive s at fixed dk -> one 8B store.
#pragma unroll
    for (int j = 0; j < 4; ++j) {
      const int col = n0 + wc * 64 + j * 16 + lr;
      const float bv = bias[col];
      const int h = col >> 6, dk = col & 63;
#pragma unroll
      for (int i = 0; i < 4; ++i) {
        const int row = m0 + wr * 64 + i * 16 + lq * 4;
        const int b = row >> 11, s = row & (SS - 1);
        uint2 pk;
        pk.x = pack2bf(acc[i][j][0] + bv, acc[i][j][1] + bv);
        pk.y = pack2bf(acc[i][j][2] + bv, acc[i][j][3] + bv);
        *(uint2*)&((u16*)outv)[(((size_t)(b * HH + h)) * DKK + dk) * SS + s] = pk;
      }
    }
  } else {
#pragma unroll
    for (int j = 0; j < 4; ++j) {
      const int col = n0 + wc * 64 + j * 16 + lr;
      const float bv = bias[col];
#pragma unroll
      for (int i = 0; i < 4; ++i) {
#pragma unroll
        for (int r = 0; r < 4; ++r) {
          const int row = m0 + wr * 64 + i * 16 + lq * 4 + r;
          const float v = acc[i][j][r] + bv;
          if (EPI == 0) {
            ((u16*)outv)[(size_t)row * NN + col] = f2bf(v);
          } else if (EPI == 1) {
            ((u16*)outv)[(size_t)row * NN + col] = f2bf(v * QSCALE);
          } else {
            ((float*)outv)[(size_t)row * NN + col] = v;
          }
        }
      }
    }
  }
}

// ---------------- flash attention, no-max softmax, 256 q/block, 64 q/wave ----------------
// Q,K bf16 [B,S,D] (Q pre-scaled by QSCALE); Vt bf16 [B,H,DK,S]; ctx bf16 [B,S,D].
// 4 waves x 64 queries (4 strips of 16). K-tiles of 64 keys.
// Grid: x = bh (same-bh q-blocks land on one XCD under round-robin), y = q-block.
__global__ __launch_bounds__(256) void attn_kernel(const u16* __restrict__ Q,
                                                   const u16* __restrict__ Kmat,
                                                   const u16* __restrict__ Vt,
                                                   u16* __restrict__ ctx) {
  __shared__ __align__(16) u16 Ks[64 * 64];        // chunk c=2t+half: keys t*16..+15
  __shared__ __align__(16) u16 Vs[64 * 64];        // chunk c=2t+half: dk t*16..+15
  __shared__ __align__(16) u16 Ps[4 * 2 * PS_REGION];  // per-wave, 2 ping-pong regions
  const int tid = threadIdx.x;
  const int w = tid >> 6, lane = tid & 63;
  const int lr = lane & 15, lq = lane >> 4;
  const int bh = blockIdx.x, b = bh >> 4, h = bh & 15;
  const int q0 = blockIdx.y * 256;

  short8v qf[4][2];
  {
    const u16* qp = Q + ((size_t)(b * SS + q0 + w * 64 + lr)) * DD + h * 64 + lq * 8;
#pragma unroll
    for (int s = 0; s < 4; ++s) {
      qf[s][0] = *(const short8v*)(qp + (size_t)s * 16 * DD);
      qf[s][1] = *(const short8v*)(qp + (size_t)s * 16 * DD + 32);
    }
  }
  floatx4 o[4][4] = {};
  float l_part[4][4] = {};

  const u16* kp = Kmat + ((size_t)(b * SS + w * 16 + lr)) * DD + h * 64 + lq * 8;
  const u16* vp = Vt + (((size_t)(b * HH + h)) * DKK + w * 16 + lr) * SS + lq * 8;

  for (int kt = 0; kt < SS / 64; ++kt) {
    load_lds16(kp,      &Ks[(2 * w) * 512]);
    load_lds16(kp + 32, &Ks[(2 * w + 1) * 512]);
    load_lds16(vp,      &Vs[(2 * w) * 512]);
    load_lds16(vp + 32, &Vs[(2 * w + 1) * 512]);
    kp += 64 * DD; vp += 64;
    __syncthreads();

    // S^(strips): D[row=q(lq*4+r)][col=key(t*16+lr)] per strip of 16 q
    floatx4 sc[4][4] = {};
#pragma unroll
    for (int t = 0; t < 4; ++t) {
      short8v kb0 = *(const short8v*)&Ks[t * 1024 + lane * 8];
      short8v kb1 = *(const short8v*)&Ks[t * 1024 + 512 + lane * 8];
#pragma unroll
      for (int s = 0; s < 4; ++s) {
        sc[s][t] = mfma_bf16(qf[s][0], kb0, sc[s][t]);
        sc[s][t] = mfma_bf16(qf[s][1], kb1, sc[s][t]);
      }
    }

    short8v pa[4][2];
#pragma unroll
    for (int s = 0; s < 4; ++s) {
#pragma unroll
      for (int t = 0; t < 4; ++t) {
#pragma unroll
        for (int r = 0; r < 4; ++r) {
          const float e = __builtin_amdgcn_exp2f(sc[s][t][r]);
          sc[s][t][r] = e;
          l_part[s][r] += e;
        }
      }
      // write P[q][key]: chunk=key>>3, row=q, j=key&7 (conflict-free padded)
      u16* pw = &Ps[(w * 2 + (s & 1)) * PS_REGION];
#pragma unroll
      for (int t = 0; t < 4; ++t) {
        const int base = (2 * t + (lr >> 3)) * PS_CS + (lr & 7);
#pragma unroll
        for (int r = 0; r < 4; ++r)
          pw[base + (lq * 4 + r) * PS_RS] = f2bf(sc[s][t][r]);
      }
      // read A-frag: m=q=lr, k-octet: chunk lq (keys 0..31), chunk 4+lq (keys 32..63)
      {
        const u16* rp0 = pw + lq * PS_CS + lr * PS_RS;
        const u16* rp1 = pw + (4 + lq) * PS_CS + lr * PS_RS;
        short4v a0 = *(const short4v*)rp0;
        short4v a1 = *(const short4v*)(rp0 + 4);
        short4v a2 = *(const short4v*)rp1;
        short4v a3 = *(const short4v*)(rp1 + 4);
        pa[s][0] = __builtin_shufflevector(a0, a1, 0, 1, 2, 3, 4, 5, 6, 7);
        pa[s][1] = __builtin_shufflevector(a2, a3, 0, 1, 2, 3, 4, 5, 6, 7);
      }
    }

#pragma unroll
    for (int t = 0; t < 4; ++t) {
      short8v vb0 = *(const short8v*)&Vs[t * 1024 + lane * 8];
      short8v vb1 = *(const short8v*)&Vs[t * 1024 + 512 + lane * 8];
#pragma unroll
      for (int s = 0; s < 4; ++s) {
        o[s][t] = mfma_bf16(pa[s][0], vb0, o[s][t]);
        o[s][t] = mfma_bf16(pa[s][1], vb1, o[s][t]);
      }
    }
    __syncthreads();
  }

  float inv[4][4];
#pragma unroll
  for (int s = 0; s < 4; ++s)
#pragma unroll
    for (int r = 0; r < 4; ++r) {
      float l = l_part[s][r];
      l += __shfl_xor(l, 1); l += __shfl_xor(l, 2);
      l += __shfl_xor(l, 4); l += __shfl_xor(l, 8);
      inv[s][r] = 1.0f / l;
    }

#pragma unroll
  for (int s = 0; s < 4; ++s)
#pragma unroll
    for (int r = 0; r < 4; ++r) {
      const int sq = q0 + w * 64 + s * 16 + lq * 4 + r;
      u16* cp = ctx + ((size_t)(b * SS + sq)) * DD + h * 64;
      const float iv = inv[s][r];
#pragma unroll
      for (int t = 0; t < 4; ++t)
        cp[t * 16 + lr] = f2bf(o[s][t][r] * iv);
    }
}

// ---------------- launch ----------------
extern "C" void kernel_launch(void* const* d_in, const int* in_sizes, int n_in,
                              void* d_out, int out_size, void* d_ws, size_t ws_size,
                              hipStream_t stream) {
  const float* query = (const float*)d_in[0];
  const float* key   = (const float*)d_in[1];
  const float* value = (const float*)d_in[2];
  const float* Wq = (const float*)d_in[3];  const float* bq = (const float*)d_in[4];
  const float* Wk = (const float*)d_in[5];  const float* bk = (const float*)d_in[6];
  const float* Wv = (const float*)d_in[7];  const float* bv = (const float*)d_in[8];
  const float* Wo = (const float*)d_in[9];  const float* bo = (const float*)d_in[10];
  float* out = (float*)d_out;

  char* ws = (char*)d_ws;
  size_t off = 0;
  u16* Wq_b = (u16*)(ws + off); off += (size_t)DD * DD * 2;
  u16* Wk_b = (u16*)(ws + off); off += (size_t)DD * DD * 2;
  u16* Wv_b = (u16*)(ws + off); off += (size_t)DD * DD * 2;
  u16* Wo_b = (u16*)(ws + off); off += (size_t)DD * DD * 2;
  u16* Qb   = (u16*)(ws + off); off += (size_t)MM * DD * 2;  // scaled Q, [B,S,D]
  u16* Kb   = (u16*)(ws + off); off += (size_t)MM * DD * 2;  // [B,S,D]
  u16* Vtb  = (u16*)(ws + off); off += (size_t)MM * DD * 2;  // [B,H,DK,S]
  u16* qc   = (u16*)(ws + off);
  u16* ctxb = qc;                  off += (size_t)MM * DD * 2;  // ctx aliases qc
  u16* kc = (u16*)d_out;                      // scratch in d_out (overwritten last)
  u16* vc = (u16*)d_out + (size_t)MM * DD;

  const int wn = DD * DD, an = MM * DD;
  cvt_bf16<<<wn / 2048, 256, 0, stream>>>(Wq, Wq_b, wn);
  cvt_bf16<<<wn / 2048, 256, 0, stream>>>(Wk, Wk_b, wn);
  cvt_bf16<<<wn / 2048, 256, 0, stream>>>(Wv, Wv_b, wn);
  cvt_bf16<<<wn / 2048, 256, 0, stream>>>(Wo, Wo_b, wn);
  cvt_bf16<<<an / 2048, 256, 0, stream>>>(query, qc, an);
  cvt_bf16<<<an / 2048, 256, 0, stream>>>(key,   kc, an);
  cvt_bf16<<<an / 2048, 256, 0, stream>>>(value, vc, an);

  dim3 gg(MM / 128, NN / 128);
  gemm_bt<1><<<gg, 256, 0, stream>>>(qc, Wq_b, bq, Qb);
  gemm_bt<0><<<gg, 256, 0, stream>>>(kc, Wk_b, bk, Kb);
  gemm_bt<2><<<gg, 256, 0, stream>>>(vc, Wv_b, bv, Vtb);

  attn_kernel<<<dim3(BB * HH, SS / 256), 256, 0, stream>>>(Qb, Kb, Vtb, ctxb);

  gemm_bt<3><<<gg, 256, 0, stream>>>(ctxb, Wo_b, bo, out);
}

// Round 6
// 421.183 us; speedup vs baseline: 1.1604x; 1.1604x over previous
//
#include <hip/hip_runtime.h>

typedef unsigned short u16;
typedef unsigned int u32;
typedef __attribute__((ext_vector_type(8))) short short8v;
typedef __attribute__((ext_vector_type(4))) short short4v;
typedef __attribute__((ext_vector_type(4))) float floatx4;

#define BB 4
#define SS 2048
#define DD 1024
#define HH 16
#define DKK 64
#define MM (BB * SS)   // 8192
#define KK DD
#define NN DD
// log2(e)/sqrt(DK): folded into Q projection so scores feed exp2 directly
#define QSCALE 0.18033688011112042f

// Ps padded layout (r3-verified conflict-free): row stride 12 u16, chunk stride 200 u16
#define PS_RS 12
#define PS_CS 200
#define PS_REGION 1600  // 8 chunks of 8 keys x 16 q rows

__device__ __forceinline__ u16 f2bf(float f) {
  union { __bf16 h; u16 u; } r; r.h = (__bf16)f; return r.u;
}
__device__ __forceinline__ u32 pack2bf(float a, float b) {
  union { u32 u; __bf16 h[2]; } r;
  r.h[0] = (__bf16)a; r.h[1] = (__bf16)b; return r.u;
}
__device__ __forceinline__ short8v cat44(short4v a, short4v b) {
  return __builtin_shufflevector(a, b, 0, 1, 2, 3, 4, 5, 6, 7);
}

__device__ __forceinline__ void load_lds16(const void* g, void* l) {
  __builtin_amdgcn_global_load_lds((const __attribute__((address_space(1))) void*)g,
                                   (__attribute__((address_space(3))) void*)l, 16, 0, 0);
}

__device__ __forceinline__ floatx4 mfma_k32(short8v a, short8v b, floatx4 c) {
  return __builtin_amdgcn_mfma_f32_16x16x32_bf16(a, b, c, 0, 0, 0);
}

// ---------------- fp32 -> bf16 converts (fused launches) ----------------
__global__ __launch_bounds__(256) void cvt_w4(const float* __restrict__ w0,
                                              const float* __restrict__ w1,
                                              const float* __restrict__ w2,
                                              const float* __restrict__ w3,
                                              u16* __restrict__ out) {
  const int y = blockIdx.y;
  const float* in = (y == 0) ? w0 : (y == 1) ? w1 : (y == 2) ? w2 : w3;
  u16* o = out + (size_t)y * DD * DD;
  const int i = (blockIdx.x * 256 + threadIdx.x) * 8;
  float4 a = *(const float4*)(in + i);
  float4 b = *(const float4*)(in + i + 4);
  uint4 v;
  v.x = pack2bf(a.x, a.y); v.y = pack2bf(a.z, a.w);
  v.z = pack2bf(b.x, b.y); v.w = pack2bf(b.z, b.w);
  *(uint4*)(o + i) = v;
}

__global__ __launch_bounds__(256) void cvt_a3(const float* __restrict__ a0,
                                              const float* __restrict__ a1,
                                              const float* __restrict__ a2,
                                              u16* __restrict__ o0, u16* __restrict__ o1,
                                              u16* __restrict__ o2) {
  const int y = blockIdx.y;
  const float* in = (y == 0) ? a0 : (y == 1) ? a1 : a2;
  u16* o = (y == 0) ? o0 : (y == 1) ? o1 : o2;
  const int i = (blockIdx.x * 256 + threadIdx.x) * 8;
  float4 a = *(const float4*)(in + i);
  float4 b = *(const float4*)(in + i + 4);
  uint4 v;
  v.x = pack2bf(a.x, a.y); v.y = pack2bf(a.z, a.w);
  v.z = pack2bf(b.x, b.y); v.w = pack2bf(b.z, b.w);
  *(uint4*)(o + i) = v;
}

// ---------------- GEMM core: acc[4][4] = A_tile @ W_tile^T (128x128, BK=32) ----------------
// Software-pipelined: stage(k+1) issued after frag reads, overlapping the MFMAs.
__device__ __forceinline__ void gemm_tile(const u16* __restrict__ A, const u16* __restrict__ W,
                                          u16* As, u16* Bs, floatx4 (&acc)[4][4]) {
  const int tid = threadIdx.x;
  const int w = tid >> 6, lane = tid & 63;
  const int lr = lane & 15, lq = lane >> 4;
  const int wr = w >> 1, wc = w & 1;
  const u16* ga0 = A + (size_t)(2 * w * 16 + lr) * KK + lq * 8;
  const u16* ga1 = ga0 + 16 * KK;
  const u16* gb0 = W + (size_t)(2 * w * 16 + lr) * KK + lq * 8;
  const u16* gb1 = gb0 + 16 * KK;
  u16* la0 = &As[(2 * w) * 512]; u16* la1 = la0 + 512;
  u16* lb0 = &Bs[(2 * w) * 512]; u16* lb1 = lb0 + 512;

  load_lds16(ga0, la0); load_lds16(ga1, la1);
  load_lds16(gb0, lb0); load_lds16(gb1, lb1);

  for (int k0 = 0; k0 < KK; k0 += 32) {
    __syncthreads();
    short8v af[4], bf[4];
#pragma unroll
    for (int i = 0; i < 4; ++i) {
      af[i] = *(const short8v*)&As[(wr * 4 + i) * 512 + lane * 8];
      bf[i] = *(const short8v*)&Bs[(wc * 4 + i) * 512 + lane * 8];
    }
    __syncthreads();
    if (k0 + 32 < KK) {
      load_lds16(ga0 + k0 + 32, la0); load_lds16(ga1 + k0 + 32, la1);
      load_lds16(gb0 + k0 + 32, lb0); load_lds16(gb1 + k0 + 32, lb1);
    }
#pragma unroll
    for (int i = 0; i < 4; ++i)
#pragma unroll
      for (int j = 0; j < 4; ++j)
        acc[i][j] = mfma_k32(af[i], bf[j], acc[i][j]);
  }
}

// ---------------- fused QKV projection (blockIdx.z selects q/k/v) ----------------
__global__ __launch_bounds__(256) void proj_gemm(
    const u16* __restrict__ qc, const u16* __restrict__ kc, const u16* __restrict__ vc,
    const u16* __restrict__ Wq, const u16* __restrict__ Wk, const u16* __restrict__ Wv,
    const float* __restrict__ bq, const float* __restrict__ bk, const float* __restrict__ bv,
    u16* __restrict__ Qb, u16* __restrict__ Kb, u16* __restrict__ Vtb) {
  __shared__ __align__(16) u16 As[128 * 32];
  __shared__ __align__(16) u16 Bs[128 * 32];
  const int z = blockIdx.z;
  const u16* A = (z == 0) ? qc : (z == 1) ? kc : vc;
  const u16* W = (z == 0) ? Wq : (z == 1) ? Wk : Wv;
  const float* bias = (z == 0) ? bq : (z == 1) ? bk : bv;
  const int m0 = blockIdx.x * 128, n0 = blockIdx.y * 128;

  floatx4 acc[4][4] = {};
  gemm_tile(A + (size_t)m0 * KK, W + (size_t)n0 * KK, As, Bs, acc);

  const int tid = threadIdx.x;
  const int w = tid >> 6, lane = tid & 63;
  const int lr = lane & 15, lq = lane >> 4;
  const int wr = w >> 1, wc = w & 1;

  if (z == 2) {
    // V^T store [B,H,DK,S]: r=0..3 are consecutive s -> packed b64 (r3-verified)
#pragma unroll
    for (int j = 0; j < 4; ++j) {
      const int col = n0 + wc * 64 + j * 16 + lr;
      const float bv_ = bias[col];
      const int h = col >> 6, dk = col & 63;
#pragma unroll
      for (int i = 0; i < 4; ++i) {
        const int row = m0 + wr * 64 + i * 16 + lq * 4;
        const int b = row >> 11, s = row & (SS - 1);
        uint2 pk;
        pk.x = pack2bf(acc[i][j][0] + bv_, acc[i][j][1] + bv_);
        pk.y = pack2bf(acc[i][j][2] + bv_, acc[i][j][3] + bv_);
        *(uint2*)&Vtb[(((size_t)(b * HH + h)) * DKK + dk) * SS + s] = pk;
      }
    }
  } else {
    u16* out = (z == 0) ? Qb : Kb;
    const float sc = (z == 0) ? QSCALE : 1.0f;
#pragma unroll
    for (int j = 0; j < 4; ++j) {
      const int col = n0 + wc * 64 + j * 16 + lr;
      const float bv_ = bias[col];
#pragma unroll
      for (int i = 0; i < 4; ++i)
#pragma unroll
        for (int r = 0; r < 4; ++r) {
          const int row = m0 + wr * 64 + i * 16 + lq * 4 + r;
          out[(size_t)row * NN + col] = f2bf((acc[i][j][r] + bv_) * sc);
        }
    }
  }
}

// ---------------- output GEMM (fp32 store) ----------------
__global__ __launch_bounds__(256) void out_gemm(const u16* __restrict__ A,
                                                const u16* __restrict__ W,
                                                const float* __restrict__ bias,
                                                float* __restrict__ out) {
  __shared__ __align__(16) u16 As[128 * 32];
  __shared__ __align__(16) u16 Bs[128 * 32];
  const int m0 = blockIdx.x * 128, n0 = blockIdx.y * 128;
  floatx4 acc[4][4] = {};
  gemm_tile(A + (size_t)m0 * KK, W + (size_t)n0 * KK, As, Bs, acc);

  const int tid = threadIdx.x;
  const int w = tid >> 6, lane = tid & 63;
  const int lr = lane & 15, lq = lane >> 4;
  const int wr = w >> 1, wc = w & 1;
#pragma unroll
  for (int j = 0; j < 4; ++j) {
    const int col = n0 + wc * 64 + j * 16 + lr;
    const float bv = bias[col];
#pragma unroll
    for (int i = 0; i < 4; ++i)
#pragma unroll
      for (int r = 0; r < 4; ++r) {
        const int row = m0 + wr * 64 + i * 16 + lq * 4 + r;
        out[(size_t)row * NN + col] = acc[i][j][r] + bv;
      }
  }
}

// ---------------- flash attention: r2 geometry + r3 conflict-free Ps ----------------
// Non-transposed scores: S = Q·K^T via mfma(A=Q-frag, B=K-frag), D[q][key].
// P round-trips through padded Ps (LDS) to become the PV A-operand.
// 4 waves x 32 q (2 strips of 16); K-tiles of 64 keys. Grid x=bh (XCD L2 locality).
__global__ __launch_bounds__(256, 3) void attn_kernel(const u16* __restrict__ Q,
                                                      const u16* __restrict__ Kmat,
                                                      const u16* __restrict__ Vt,
                                                      u16* __restrict__ ctx) {
  __shared__ __align__(16) u16 Ks[64 * 64];  // chunk 2t+half: key 16t+lr, dk 32*half+8lq+j
  __shared__ __align__(16) u16 Vs[64 * 64];  // chunk 2t+half: dk 16t+lr, key 32*half+8lq+j
  __shared__ __align__(16) u16 Ps[4 * 2 * PS_REGION];  // per-wave, per-strip-parity
  const int tid = threadIdx.x;
  const int w = tid >> 6, lane = tid & 63;
  const int lr = lane & 15, lq = lane >> 4;
  const int bh = blockIdx.x, b = bh >> 4, h = bh & 15;
  const int q0 = blockIdx.y * 128;

  // Q as A-operand: lane m=lr=q-in-strip, k-slot (lq, j) -> dk = 32*half + 8lq + j
  short8v qf[2][2];
  {
    const u16* qp = Q + ((size_t)(b * SS + q0 + w * 32 + lr)) * DD + h * 64 + lq * 8;
    qf[0][0] = *(const short8v*)qp;
    qf[0][1] = *(const short8v*)(qp + 32);
    qf[1][0] = *(const short8v*)(qp + 16 * DD);
    qf[1][1] = *(const short8v*)(qp + 16 * DD + 32);
  }
  floatx4 o[2][4] = {};     // o[s][t]: row q=4lq+r, col dk=16t+lr
  float l_part[2][4] = {};  // per-lane partial denom for query row r of strip s

  const u16* kp = Kmat + ((size_t)(b * SS + w * 16 + lr)) * DD + h * 64 + lq * 8;
  const u16* vp = Vt + (((size_t)(b * HH + h)) * DKK + w * 16 + lr) * SS + lq * 8;

  for (int kt = 0; kt < SS / 64; ++kt) {
    load_lds16(kp,      &Ks[(2 * w) * 512]);
    load_lds16(kp + 32, &Ks[(2 * w + 1) * 512]);
    load_lds16(vp,      &Vs[(2 * w) * 512]);
    load_lds16(vp + 32, &Vs[(2 * w + 1) * 512]);
    kp += 64 * DD; vp += 64;
    __syncthreads();

    // S: D[row=q(4lq+r)][col=key(16t+lr)] per strip
    floatx4 sc[2][4] = {};
#pragma unroll
    for (int t = 0; t < 4; ++t) {
      short8v kb0 = *(const short8v*)&Ks[t * 1024 + lane * 8];
      short8v kb1 = *(const short8v*)&Ks[t * 1024 + 512 + lane * 8];
#pragma unroll
      for (int s = 0; s < 2; ++s) {
        sc[s][t] = mfma_k32(qf[s][0], kb0, sc[s][t]);
        sc[s][t] = mfma_k32(qf[s][1], kb1, sc[s][t]);
      }
    }

    short8v pa[2][2];
#pragma unroll
    for (int s = 0; s < 2; ++s) {
#pragma unroll
      for (int t = 0; t < 4; ++t) {
#pragma unroll
        for (int r = 0; r < 4; ++r) {
          const float e = __builtin_amdgcn_exp2f(sc[s][t][r]);
          sc[s][t][r] = e;
          l_part[s][r] += e;
        }
      }
      // write P[q][key]: chunk=key>>3, row=q, col=key&7 (padded, conflict-free)
      u16* pw = &Ps[(w * 2 + (s & 1)) * PS_REGION];
#pragma unroll
      for (int t = 0; t < 4; ++t) {
        const int base = (2 * t + (lr >> 3)) * PS_CS + (lr & 7);
#pragma unroll
        for (int r = 0; r < 4; ++r)
          pw[base + (lq * 4 + r) * PS_RS] = f2bf(sc[s][t][r]);
      }
      // read A-frag: m=q=lr, slot (lq,j) -> key 8lq+j (pa[0]) / 32+8lq+j (pa[1])
      {
        const u16* rp0 = pw + lq * PS_CS + lr * PS_RS;
        const u16* rp1 = pw + (4 + lq) * PS_CS + lr * PS_RS;
        pa[s][0] = cat44(*(const short4v*)rp0, *(const short4v*)(rp0 + 4));
        pa[s][1] = cat44(*(const short4v*)rp1, *(const short4v*)(rp1 + 4));
      }
    }

#pragma unroll
    for (int t = 0; t < 4; ++t) {
      short8v vb0 = *(const short8v*)&Vs[t * 1024 + lane * 8];
      short8v vb1 = *(const short8v*)&Vs[t * 1024 + 512 + lane * 8];
#pragma unroll
      for (int s = 0; s < 2; ++s) {
        o[s][t] = mfma_k32(pa[s][0], vb0, o[s][t]);
        o[s][t] = mfma_k32(pa[s][1], vb1, o[s][t]);
      }
    }
    __syncthreads();
  }

  float inv[2][4];
#pragma unroll
  for (int s = 0; s < 2; ++s)
#pragma unroll
    for (int r = 0; r < 4; ++r) {
      float l = l_part[s][r];
      l += __shfl_xor(l, 1); l += __shfl_xor(l, 2);
      l += __shfl_xor(l, 4); l += __shfl_xor(l, 8);
      inv[s][r] = 1.0f / l;
    }

#pragma unroll
  for (int s = 0; s < 2; ++s)
#pragma unroll
    for (int r = 0; r < 4; ++r) {
      const int sq = q0 + w * 32 + s * 16 + lq * 4 + r;
      u16* cp = ctx + ((size_t)(b * SS + sq)) * DD + h * 64;
      const float iv = inv[s][r];
#pragma unroll
      for (int t = 0; t < 4; ++t)
        cp[t * 16 + lr] = f2bf(o[s][t][r] * iv);
    }
}

// ---------------- launch ----------------
extern "C" void kernel_launch(void* const* d_in, const int* in_sizes, int n_in,
                              void* d_out, int out_size, void* d_ws, size_t ws_size,
                              hipStream_t stream) {
  const float* query = (const float*)d_in[0];
  const float* key   = (const float*)d_in[1];
  const float* value = (const float*)d_in[2];
  const float* Wq = (const float*)d_in[3];  const float* bq = (const float*)d_in[4];
  const float* Wk = (const float*)d_in[5];  const float* bk = (const float*)d_in[6];
  const float* Wv = (const float*)d_in[7];  const float* bv = (const float*)d_in[8];
  const float* Wo = (const float*)d_in[9];  const float* bo = (const float*)d_in[10];
  float* out = (float*)d_out;

  char* ws = (char*)d_ws;
  size_t off = 0;
  u16* Wb   = (u16*)(ws + off); off += (size_t)4 * DD * DD * 2;  // Wq,Wk,Wv,Wo bf16
  u16* Qb   = (u16*)(ws + off); off += (size_t)MM * DD * 2;      // scaled Q [B,S,D]
  u16* Kb   = (u16*)(ws + off); off += (size_t)MM * DD * 2;      // [B,S,D]
  u16* Vtb  = (u16*)(ws + off); off += (size_t)MM * DD * 2;      // [B,H,DK,S]
  u16* qc   = (u16*)(ws + off);
  u16* ctxb = qc;               off += (size_t)MM * DD * 2;      // ctx aliases qc
  u16* kc = (u16*)d_out;                       // scratch in d_out (overwritten last)
  u16* vc = (u16*)d_out + (size_t)MM * DD;
  u16* Wq_b = Wb, *Wk_b = Wb + (size_t)DD * DD, *Wv_b = Wb + (size_t)2 * DD * DD,
     *Wo_b = Wb + (size_t)3 * DD * DD;

  const int wn = DD * DD, an = MM * DD;
  cvt_w4<<<dim3(wn / 2048, 4), 256, 0, stream>>>(Wq, Wk, Wv, Wo, Wb);
  cvt_a3<<<dim3(an / 2048, 3), 256, 0, stream>>>(query, key, value, qc, kc, vc);

  proj_gemm<<<dim3(MM / 128, NN / 128, 3), 256, 0, stream>>>(
      qc, kc, vc, Wq_b, Wk_b, Wv_b, bq, bk, bv, Qb, Kb, Vtb);

  attn_kernel<<<dim3(BB * HH, SS / 128), 256, 0, stream>>>(Qb, Kb, Vtb, ctxb);

  out_gemm<<<dim3(MM / 128, NN / 128), 256, 0, stream>>>(ctxb, Wo_b, bo, out);
}